// Round 3
// baseline (209.635 us; speedup 1.0000x reference)
//
#include <hip/hip_runtime.h>

// Problem constants (fixed by reference)
#define B_ 4
#define T_ 4096
#define D_ 256
#define H_ 64
#define NBT (B_ * T_)         // 16384
#define NBTH (B_ * T_ * H_)   // 1048576

typedef __bf16 bf16x8 __attribute__((ext_vector_type(8)));
typedef float f32x4 __attribute__((ext_vector_type(4)));

__device__ __forceinline__ unsigned short f2bf(float f) {
  union { float f; unsigned int u; } v; v.f = f;
  unsigned int u = v.u;
  return (unsigned short)((u + 0x7fffu + ((u >> 16) & 1u)) >> 16);  // RNE
}

#if __has_builtin(__builtin_amdgcn_cvt_pk_bf16_f32)
typedef __bf16 bf16x2_t __attribute__((ext_vector_type(2)));
__device__ __forceinline__ unsigned int pk2(float a, float b) {
  union { bf16x2_t v; unsigned int u; } c;
  c.v = __builtin_amdgcn_cvt_pk_bf16_f32(a, b);   // lo = a, hi = b
  return c.u;
}
#else
__device__ __forceinline__ unsigned int pk2(float a, float b) {
  return (unsigned int)f2bf(a) | ((unsigned int)f2bf(b) << 16);
}
#endif

#if __has_builtin(__builtin_amdgcn_exp2f)
#define EXP2(x) __builtin_amdgcn_exp2f(x)
#else
#define EXP2(x) exp2f(x)
#endif

// log2(e)/16 — folds the 1/sqrt(256) logit scale AND exp->exp2 into Wq
// (RoPE rotation is linear: scale commutes).
#define QSCALE 0.09016844f

// direct global->LDS 16B copy; LDS dest must be WAVE-UNIFORM (HW adds
// lane*16), global src is per-lane.
__device__ __forceinline__ void gload_lds16(const void* g, void* l) {
  __builtin_amdgcn_global_load_lds(
      (__attribute__((address_space(1))) void*)(g),
      (__attribute__((address_space(3))) void*)(l), 16, 0, 0);
}

// ===========================================================================
// FRAGMENT-ORDERED GLOBAL LAYOUTS: every MFMA operand fragment
// (64 lanes x 16 B) is stored contiguously, so consumers issue
// perfectly-coalesced global b128 loads (or 16B global_load_lds).
//   W:  wfrag(m, ht, c)        = ((m*4+ht)*8+c)*512    + lane*8
//   Q:  qfrag(rowblk16, half)  = (rowblk*2+half)*512   + lane*8
//   K:  kfrag(kvblk64,mt,half) = ((kvblk*4+mt)*2+half)*512 + lane*8
//   V:  vfrag(kvblk64,hh,half) = ((kvblk*4+hh)*2+half)*512 + lane*8
// (rowblk/kvblk are GLOBAL over B*T; lane = quad*16+l16.)
// ===========================================================================

// ---------------------------------------------------------------------------
// Kernel P: W transpose + bf16 cast + fragment-order emit. 12 blocks.
// Also zeroes the split-KV finisher counters (must precede attn in-stream).
// ---------------------------------------------------------------------------
__global__ __launch_bounds__(256) void prep_w_kernel(
    const float* __restrict__ Wq, const float* __restrict__ Wk,
    const float* __restrict__ Wv, unsigned short* __restrict__ wt,
    int* __restrict__ cnt) {
  if (blockIdx.x == 0 && threadIdx.x < 64) cnt[threadIdx.x] = 0;
  const int m = blockIdx.x >> 2;        // 0..2: which matrix
  const int cp = blockIdx.x & 3;        // c-pair: handles c = cp*2, cp*2+1
  const float* W = (m == 0) ? Wq : (m == 1) ? Wk : Wv;
  const float scale = (m == 0) ? QSCALE : 1.f;
  __shared__ __align__(16) unsigned short tile[64][72];  // [h][d-local]
  int h = threadIdx.x & 63, dq = threadIdx.x >> 6;
  const int d0 = cp * 64;
  for (int dl = dq; dl < 64; dl += 4)
    tile[h][dl] = f2bf(W[(d0 + dl) * H_ + h] * scale);
  __syncthreads();
  int ht = threadIdx.x >> 6;            // wave = ht
  int lane = threadIdx.x & 63, quad = lane >> 4, l16 = lane & 15;
#pragma unroll
  for (int cl = 0; cl < 2; ++cl) {
    int c = cp * 2 + cl;
    bf16x8 v = *(const bf16x8*)&tile[ht * 16 + l16][cl * 32 + quad * 8];
    *(bf16x8*)&wt[(((m * 4 + ht) * 8 + c) << 9) + lane * 8] = v;
  }
}

// ---------------------------------------------------------------------------
// Kernel A: MFMA QKV projection + RoPE, fragment-ordered outputs.
// (unchanged this round)
// ---------------------------------------------------------------------------
__global__ __launch_bounds__(192) void qkv_kernel(
    const float* __restrict__ x, const unsigned short* __restrict__ wt,
    const float* __restrict__ axg, const float* __restrict__ ayg,
    unsigned short* __restrict__ qo, unsigned short* __restrict__ ko,
    unsigned short* __restrict__ vt) {
  const int row0g = blockIdx.x * 16;    // global flat row over B*T
  const int tid = threadIdx.x;
  const int w = tid / 64, lane = tid & 63, quad = lane >> 4, l16 = lane & 15;

  __shared__ unsigned short xs[16][264];      // 8.4 KB
  __shared__ unsigned short qkt[2][16][72];   // q/k transpose, per-wave
  __shared__ unsigned short vsh[64][16];      // v transpose (wave 2 only)

  // stage x-tile: 16 rows x 256 f32 = 1024 float4, convert to bf16
  const float4* xb = (const float4*)(x + (size_t)row0g * D_);
  for (int i = tid; i < 1024; i += 192) {
    float4 v = xb[i];
    int r = i >> 6, c4 = (i & 63) << 2;
    *(unsigned int*)&xs[r][c4] = pk2(v.x, v.y);
    *(unsigned int*)&xs[r][c4 + 2] = pk2(v.z, v.w);
  }
  __syncthreads();

  // x fragments: A[m=l16][k=c*32+quad*8+j]
  bf16x8 xf[8];
#pragma unroll
  for (int c = 0; c < 8; ++c)
    xf[c] = *(const bf16x8*)&xs[l16][c * 32 + quad * 8];

  // GEMM for matrix w: W-frags coalesced from global
  const unsigned short* wb = wt + (((size_t)w * 4) * 8 << 9);
  f32x4 acc[4];
#pragma unroll
  for (int ht = 0; ht < 4; ++ht) acc[ht] = (f32x4){0.f, 0.f, 0.f, 0.f};
#pragma unroll
  for (int c = 0; c < 8; ++c) {
#pragma unroll
    for (int ht = 0; ht < 4; ++ht) {
      bf16x8 wf = *(const bf16x8*)&wb[((ht * 8 + c) << 9) + lane * 8];
      acc[ht] = __builtin_amdgcn_mfma_f32_16x16x32_bf16(xf[c], wf, acc[ht],
                                                        0, 0, 0);
    }
  }

  const int row0loc = row0g & (T_ - 1);
  if (w < 2) {
    // RoPE on C/D layout, then LDS transpose -> fragment-order store
    const float sgn = (l16 & 1) ? 1.f : -1.f;
#pragma unroll
    for (int ht = 0; ht < 4; ++ht) {
      int hh = ht * 16 + l16;
      int pidx = (hh & 31) >> 1;
      const float* ab = (hh >= 32) ? ayg : axg;
#pragma unroll
      for (int r = 0; r < 4; ++r) {
        int t = row0loc + quad * 4 + r;
        float s, c;
        __sincosf(ab[t * 16 + pidx], &s, &c);
        float val = acc[ht][r];
        float par = __shfl_xor(val, 1);   // RoPE pair partner h^1
        qkt[w][quad * 4 + r][hh] = f2bf(val * c + sgn * par * s);
      }
    }
    asm volatile("s_waitcnt lgkmcnt(0)" ::: "memory");  // intra-wave
    unsigned short* dst;
    size_t base;
    if (w == 0) {
      dst = qo;
      base = ((size_t)(row0g >> 4) * 2) << 9;
    } else {
      dst = ko;
      base = ((size_t)((row0g >> 6) * 8 + ((row0g >> 4) & 3) * 2)) << 9;
    }
#pragma unroll
    for (int half = 0; half < 2; ++half) {
      bf16x8 v = *(const bf16x8*)&qkt[w][l16][half * 32 + quad * 8];
      *(bf16x8*)&dst[base + half * 512 + lane * 8] = v;
    }
  } else {
    // v: C/D -> LDS transpose -> partial fragment-order store
#pragma unroll
    for (int ht = 0; ht < 4; ++ht)
#pragma unroll
      for (int r = 0; r < 4; ++r)
        vsh[ht * 16 + l16][quad * 4 + r] = f2bf(acc[ht][r]);
    asm volatile("s_waitcnt lgkmcnt(0)" ::: "memory");  // intra-wave
    const int kvblk = row0g >> 6;       // global 64-blk
    const int mt = (row0g >> 4) & 3;
    const int half_v = mt >> 1, qlow = (mt & 1) * 2;
#pragma unroll
    for (int it = 0; it < 2; ++it) {
      int hhx = it * 2 + (quad >> 1);
      int qp = qlow + (quad & 1);
      bf16x8 v = *(const bf16x8*)&vsh[hhx * 16 + l16][(quad & 1) * 8];
      *(bf16x8*)&vt[((((size_t)kvblk * 4 + hhx) * 2 + half_v) << 9) +
                    (qp * 16 + l16) * 8] = v;
    }
  }
}

// ---------------------------------------------------------------------------
// Kernel B: flash attention, split-KV, fixed max (logits bounded; m=0
// softmax is exact math), exp2 domain.  Round-3 changes:
//  * K/V tiles staged ONCE per block into LDS via global_load_lds (16B),
//    double-buffered, counted vmcnt(4) (never 0 in-loop), raw s_barrier x2
//    per tile.  All 4 waves read fragments from LDS -> global/L2 K/V
//    traffic drops 4x (268 -> 67 MB).  Stage of tile kb+2 is issued right
//    before the PV MFMA burst so its latency hides under MFMA.
//  * combine fused: after partial writes, threadfence + per-(b,q0) atomic
//    counter; the LAST split block re-reads the NS partials (L2/L3-hot)
//    and writes the final output.  combine_kernel deleted.
// LDS: Kbuf 16K + Vbuf 16K + Ps 36K = 68 KB -> 2 blocks/CU.
// ---------------------------------------------------------------------------
#define LDP 72

__global__ __launch_bounds__(256, 2) void attn_kernel(
    const unsigned short* __restrict__ qfg, const unsigned short* __restrict__ kfg,
    const unsigned short* __restrict__ vfg, float* __restrict__ opart,
    float* __restrict__ lpart, int* __restrict__ cnt, float* __restrict__ out,
    int kv_len) {
  const int split = blockIdx.x >> 6;    // 64 blocks per split
  const int rem = blockIdx.x & 63;
  const int b = rem >> 4;
  const int q0 = (rem & 15) * 256;
  const int tid = threadIdx.x;
  const int w = tid >> 6, lane = tid & 63, quad = lane >> 4, l16 = lane & 15;

  __shared__ __align__(16) unsigned short Kbuf[2][4096];   // 16 KB
  __shared__ __align__(16) unsigned short Vbuf[2][4096];   // 16 KB
  __shared__ unsigned short Ps[4][64 * LDP];               // 36 KB
  __shared__ int last_flag;

  // Q fragments (B-operand), coalesced from fragment-ordered qfg
  bf16x8 qf[4][2];
#pragma unroll
  for (int u = 0; u < 4; ++u) {
    size_t rb = (size_t)(b * T_ + q0 + w * 64 + u * 16) >> 4;
#pragma unroll
    for (int half = 0; half < 2; ++half)
      qf[u][half] = *(const bf16x8*)&qfg[((rb * 2 + half) << 9) + lane * 8];
  }

  const int kvb0 = (b * T_ + split * kv_len) >> 6;
  const int nkvb = kv_len >> 6;

  // wave w stages K frags {2w,2w+1} and V frags {2w,2w+1}: 4 x 16B/thread.
  // LDS dest is wave-uniform; global src per-lane.
  auto stage = [&](int kb, int buf) {
    const unsigned short* kfb = kfg + ((size_t)(kvb0 + kb) << 12);
    const unsigned short* vfb = vfg + ((size_t)(kvb0 + kb) << 12);
#pragma unroll
    for (int i = 0; i < 2; ++i) {
      int f = w * 2 + i;
      gload_lds16(kfb + (f << 9) + lane * 8, &Kbuf[buf][f * 512]);
      gload_lds16(vfb + (f << 9) + lane * 8, &Vbuf[buf][f * 512]);
    }
  };

  stage(0, 0);
  if (nkvb > 1) stage(1, 1);

  f32x4 oacc[4][4];
  float lsum[4] = {0.f, 0.f, 0.f, 0.f};
  const f32x4 vzero = {0.f, 0.f, 0.f, 0.f};
#pragma unroll
  for (int u = 0; u < 4; ++u)
#pragma unroll
    for (int hh = 0; hh < 4; ++hh) oacc[u][hh] = vzero;

  for (int kb = 0; kb < nkvb; ++kb) {
    const int cur = kb & 1;
    // wait tile kb landed (tile kb+1's 4 loads may stay in flight)
    if (kb + 1 < nkvb) asm volatile("s_waitcnt vmcnt(4)" ::: "memory");
    else               asm volatile("s_waitcnt vmcnt(0)" ::: "memory");
    __builtin_amdgcn_sched_barrier(0);
    __builtin_amdgcn_s_barrier();        // #1: tile kb visible to all waves
    __builtin_amdgcn_sched_barrier(0);

    // S^T: D[kv=mt*16+quad*4+r][q=u*16+l16]; exp2 + pack fused per (mt,u)
#pragma unroll
    for (int mt = 0; mt < 4; ++mt) {
      bf16x8 k0 = *(const bf16x8*)&Kbuf[cur][(mt * 2 + 0) * 512 + lane * 8];
      bf16x8 k1 = *(const bf16x8*)&Kbuf[cur][(mt * 2 + 1) * 512 + lane * 8];
#pragma unroll
      for (int u = 0; u < 4; ++u) {
        f32x4 s = vzero;
        s = __builtin_amdgcn_mfma_f32_16x16x32_bf16(k0, qf[u][0], s, 0, 0, 0);
        s = __builtin_amdgcn_mfma_f32_16x16x32_bf16(k1, qf[u][1], s, 0, 0, 0);
        float p0 = EXP2(s[0]);
        float p1 = EXP2(s[1]);
        float p2 = EXP2(s[2]);
        float p3 = EXP2(s[3]);
        lsum[u] += (p0 + p1) + (p2 + p3);
        uint2 pk;
        pk.x = pk2(p0, p1);
        pk.y = pk2(p2, p3);
        *(uint2*)&Ps[w][(u * 16 + l16) * LDP + mt * 16 + quad * 4] = pk;
      }
    }
    asm volatile("s_waitcnt lgkmcnt(0)" ::: "memory");  // Ps visible (per-wave)

    // pull P and V fragments into regs — after this, buf[cur] is free
    bf16x8 ap[4][2];
#pragma unroll
    for (int u = 0; u < 4; ++u)
#pragma unroll
      for (int half = 0; half < 2; ++half)
        ap[u][half] =
            *(const bf16x8*)&Ps[w][(u * 16 + l16) * LDP + half * 32 + quad * 8];
    bf16x8 vr[8];
#pragma unroll
    for (int f = 0; f < 8; ++f)
      vr[f] = *(const bf16x8*)&Vbuf[cur][f * 512 + lane * 8];
    asm volatile("s_waitcnt lgkmcnt(0)" ::: "memory");
    __builtin_amdgcn_sched_barrier(0);
    __builtin_amdgcn_s_barrier();        // #2: all waves done reading buf[cur]
    __builtin_amdgcn_sched_barrier(0);
    if (kb + 2 < nkvb) stage(kb + 2, cur);   // hides under PV MFMAs below

#pragma unroll
    for (int hh = 0; hh < 4; ++hh) {
#pragma unroll
      for (int u = 0; u < 4; ++u) {
        oacc[u][hh] = __builtin_amdgcn_mfma_f32_16x16x32_bf16(
            ap[u][0], vr[hh * 2 + 0], oacc[u][hh], 0, 0, 0);
        oacc[u][hh] = __builtin_amdgcn_mfma_f32_16x16x32_bf16(
            ap[u][1], vr[hh * 2 + 1], oacc[u][hh], 0, 0, 0);
      }
    }
  }

  // epilogue: un-normalized partials; l via lane butterfly (sum over quads)
#pragma unroll
  for (int u = 0; u < 4; ++u) {
    size_t base = (size_t)(split * B_ + b) * T_ + q0 + w * 64 + u * 16;
#pragma unroll
    for (int r = 0; r < 4; ++r) {
      float* orow = opart + (base + quad * 4 + r) * H_;
#pragma unroll
      for (int hh = 0; hh < 4; ++hh) orow[hh * 16 + l16] = oacc[u][hh][r];
    }
    float l = lsum[u];
    l += __shfl_xor(l, 16);
    l += __shfl_xor(l, 32);
    if (quad == 0) lpart[base + l16] = l;   // coalesced 16-wide
  }

  // fused combine: last split block for this (b,q0) chunk normalizes.
  __threadfence();                          // release partials (device scope)
  if (tid == 0) {
    int old = atomicAdd(&cnt[rem], 1);
    last_flag = (old == (int)(gridDim.x >> 6) - 1);
  }
  __syncthreads();
  if (last_flag) {
    __threadfence();                        // acquire: see all splits' writes
    const int ns = gridDim.x >> 6;
    for (int i = tid; i < 256 * 16; i += 256) {
      int r = i >> 4, h4 = i & 15;
      size_t row = (size_t)b * T_ + q0 + r;
      float den = 0.f;
      float ax = 0.f, ay = 0.f, az = 0.f, aw = 0.f;
      for (int s = 0; s < ns; ++s) {
        den += lpart[(size_t)s * NBT + row];
        float4 o = *(const float4*)&opart[((size_t)s * NBT + row) * H_ + h4 * 4];
        ax += o.x; ay += o.y; az += o.z; aw += o.w;
      }
      float inv = 1.f / den;
      float4 res;
      res.x = ax * inv; res.y = ay * inv; res.z = az * inv; res.w = aw * inv;
      *(float4*)&out[row * H_ + h4 * 4] = res;
    }
  }
}

// ---------------------------------------------------------------------------
extern "C" void kernel_launch(void* const* d_in, const int* in_sizes, int n_in,
                              void* d_out, int out_size, void* d_ws,
                              size_t ws_size, hipStream_t stream) {
  const float* x  = (const float*)d_in[0];
  const float* Wq = (const float*)d_in[1];
  const float* Wk = (const float*)d_in[2];
  const float* Wv = (const float*)d_in[3];
  const float* ax = (const float*)d_in[4];
  const float* ay = (const float*)d_in[5];
  float* out = (float*)d_out;

  // ws: q|k|v frag-ordered bf16 (6MB) | wt bf16 (96KB) | opart | lpart | cnt
  unsigned short* qo = (unsigned short*)d_ws;
  unsigned short* ko = qo + NBTH;
  unsigned short* vt = ko + NBTH;
  unsigned short* wt = vt + NBTH;
  float* opart = (float*)(wt + 3 * H_ * D_);

  size_t fixed = (size_t)3 * NBTH * 2 + (size_t)3 * H_ * D_ * 2;
  int NS = (ws_size >= fixed + (size_t)8 * NBTH * 4 + (size_t)8 * NBT * 4 + 512)
               ? 8 : 4;
  float* lpart = opart + (size_t)NS * NBTH;
  int* cnt = (int*)(lpart + (size_t)NS * NBT);

  prep_w_kernel<<<12, 256, 0, stream>>>(Wq, Wk, Wv, wt, cnt);
  qkv_kernel<<<NBT / 16, 192, 0, stream>>>(x, wt, ax, ay, qo, ko, vt);
  attn_kernel<<<NS * 64, 256, 0, stream>>>(qo, ko, vt, opart, lpart, cnt, out,
                                           T_ / NS);
}